// Round 7
// baseline (169.016 us; speedup 1.0000x reference)
//
#include <hip/hip_runtime.h>
#include <math.h>

#ifndef __has_builtin
#define __has_builtin(x) 0
#endif

__device__ __forceinline__ float fast_exp2(float v) {
#if __has_builtin(__builtin_amdgcn_exp2f)
    return __builtin_amdgcn_exp2f(v);   // v_exp_f32 (base-2), ~1 ulp
#else
    return exp2f(v);
#endif
}

typedef float v2f __attribute__((ext_vector_type(2)));

constexpr int R = 20;   // reads per site
constexpr int C = 32;   // channels
constexpr int B = 32;   // bins

// FLOAT2 VARIANT: one thread per (site, channel-PAIR). lane -> 2 channels,
// 16 lanes cover a site's 32 channels; 4 sites per wave64. Every float2
// load/store instr covers four 128B-contiguous segments -> fully coalesced,
// 512B per wave-instruction (2x the dword variant). Halves wave count and
// VMEM instruction count; doubles per-wave bytes in flight.
//
// KDE factorization (bin centers b/31, sigma^2 = 0.01):
//   exp(-50(x - b/31)^2) = 2^{-Kx^2} * (2^{A2 x + B0})^b * 2^{-(K/961) b(b-1)}
//   K = 50*log2(e), A2 = 2K/31, B0 = -K/961.
// Inner loop: acc += P; P *= m  (2 VALU ops per bin per channel).
//
// Register budget: acc[32]x2 = 64 + xv[20] (v2f, 40) + temps ~= 110 live peak.
// __launch_bounds__(256,4) -> 128-VGPR budget (R4 lesson: must clear live set).
__global__ __launch_bounds__(256, 4) void kde_kernel(const float* __restrict__ x,
                                                     float* __restrict__ out,
                                                     int nsites) {
    int t = blockIdx.x * blockDim.x + threadIdx.x;
    int cp = t & (C / 2 - 1);          // channel pair index 0..15
    int n = t >> 4;                    // site
    if (n >= nsites) return;

    const float K  = 72.13475204444817f;    // 50 * log2(e)
    const float A2 = 4.6538549706095594f;   // 2K/31
    const float B0 = -0.07506217694531545f; // -K/961

    const float* xp = x + (size_t)n * (R * C) + 2 * cp;

    // prefetch all 20 float2 reads (10 KB per wave in flight, non-temporal)
    v2f xv[R];
#pragma unroll
    for (int r = 0; r < R; ++r)
        xv[r] = __builtin_nontemporal_load((const v2f*)&xp[(size_t)r * C]);

    float acc0[B], acc1[B];
#pragma unroll
    for (int b = 0; b < B; ++b) { acc0[b] = 0.0f; acc1[b] = 0.0f; }

#pragma unroll
    for (int r = 0; r < R; ++r) {
        float v0 = xv[r].x, v1 = xv[r].y;
        float P0 = fast_exp2(v0 * v0 * -K);        // 2^{-K x^2}
        float m0 = fast_exp2(fmaf(v0, A2, B0));    // 2^{A2 x + B0}
        float P1 = fast_exp2(v1 * v1 * -K);
        float m1 = fast_exp2(fmaf(v1, A2, B0));
#pragma unroll
        for (int b = 0; b < B; ++b) {
            acc0[b] += P0;  P0 *= m0;              // two independent chains
            acc1[b] += P1;  P1 *= m1;
        }
    }

    // epilogue: out[b] = acc[b] * (coef/R) * 2^{-(K/961) b(b-1)}
    float* op = out + (size_t)n * (B * C) + 2 * cp;
#pragma unroll
    for (int b = 0; b < B; ++b) {
        const float cb = (float)(0.19947114020071635 *
                                 exp2(-0.07506217694531545 * (double)(b * (b - 1))));
        v2f o; o.x = acc0[b] * cb; o.y = acc1[b] * cb;
        __builtin_nontemporal_store(o, (v2f*)&op[(size_t)b * C]);
    }
}

extern "C" void kernel_launch(void* const* d_in, const int* in_sizes, int n_in,
                              void* d_out, int out_size, void* d_ws, size_t ws_size,
                              hipStream_t stream) {
    const float* x = (const float*)d_in[0];
    float* out = (float*)d_out;
    int nsites = in_sizes[0] / (R * C);          // 131072
    int total = nsites * (C / 2);                // one thread per (site, channel-pair)
    int block = 256;
    int grid = (total + block - 1) / block;
    hipLaunchKernelGGL(kde_kernel, dim3(grid), dim3(block), 0, stream, x, out, nsites);
}

// Round 8
// 164.637 us; speedup vs baseline: 1.0266x; 1.0266x over previous
//
#include <hip/hip_runtime.h>
#include <math.h>

#ifndef __has_builtin
#define __has_builtin(x) 0
#endif

__device__ __forceinline__ float fast_exp2(float v) {
#if __has_builtin(__builtin_amdgcn_exp2f)
    return __builtin_amdgcn_exp2f(v);   // v_exp_f32 (base-2), ~1 ulp
#else
    return exp2f(v);
#endif
}

constexpr int R = 20;   // reads per site
constexpr int C = 32;   // channels
constexpr int B = 32;   // bins

// FINAL (restore of round-5 best, 164.7 us = 5.3 TB/s effective).
//
// One thread per (site, channel); lane = channel -> every load/store instr is
// two 128B-contiguous segments per wave64 (2 sites). Fully coalesced.
//
// KDE factorization (bin centers b/31, sigma^2 = 0.01):
//   exp(-50(x - b/31)^2) = 2^{-Kx^2} * (2^{A2 x + B0})^b * 2^{-(K/961) b(b-1)}
//   K = 50*log2(e), A2 = 2K/31, B0 = -K/961.
// Inner loop: acc[b] += P; P *= m0 (2 VALU ops/bin = algebraic minimum);
// the data-independent 2^{-(K/961) b(b-1)} factor and coef/R are folded into
// compile-time per-bin epilogue constants. Non-temporal load/store: both
// streams are touch-once, bypass cache allocation (-3.4% measured R5).
//
// Ladder: 259 (naive recurrence) -> 211 (prefetch) -> 170 (2-op inner loop)
// -> 164.7 (NT hints). Falsified: bins-outer w/ launch_bounds(256,8) spilled
// (288); chunked bins-outer neutral (167); float2 2x-width neutral (169).
// Three structures saturate at ~5.3 TB/s -> compute-interleaved mixed-stream
// ceiling for this op.
__global__ __launch_bounds__(256, 6) void kde_kernel(const float* __restrict__ x,
                                                     float* __restrict__ out,
                                                     int nsites) {
    int t = blockIdx.x * blockDim.x + threadIdx.x;
    int c = t & (C - 1);
    int n = t >> 5;
    if (n >= nsites) return;

    const float K  = 72.13475204444817f;    // 50 * log2(e)
    const float A2 = 4.6538549706095594f;   // 2K/31
    const float B0 = -0.07506217694531545f; // -K/961

    const float* xp = x + (size_t)n * (R * C) + c;

    // prefetch: all 20 loads in flight before compute (non-temporal)
    float xv[R];
#pragma unroll
    for (int r = 0; r < R; ++r) xv[r] = __builtin_nontemporal_load(&xp[(size_t)r * C]);

    float acc[B];
#pragma unroll
    for (int b = 0; b < B; ++b) acc[b] = 0.0f;

#pragma unroll
    for (int r = 0; r < R; ++r) {
        float v = xv[r];
        float P  = fast_exp2(v * v * -K);          // w0 = exp(-50 x^2)
        float m0 = fast_exp2(fmaf(v, A2, B0));     // per-bin step multiplier
#pragma unroll
        for (int b = 0; b < B; ++b) {
            acc[b] += P;       // P == w0 * m0^b
            P *= m0;
        }
    }

    // epilogue: out[b] = acc[b] * (coef/R) * 2^{-(K/961) b(b-1)}
    float* op = out + (size_t)n * (B * C) + c;
#pragma unroll
    for (int b = 0; b < B; ++b) {
        const float cb = (float)(0.19947114020071635 *
                                 exp2(-0.07506217694531545 * (double)(b * (b - 1))));
        __builtin_nontemporal_store(acc[b] * cb, &op[(size_t)b * C]);
    }
}

extern "C" void kernel_launch(void* const* d_in, const int* in_sizes, int n_in,
                              void* d_out, int out_size, void* d_ws, size_t ws_size,
                              hipStream_t stream) {
    const float* x = (const float*)d_in[0];
    float* out = (float*)d_out;
    int nsites = in_sizes[0] / (R * C);          // 131072
    int total = nsites * C;                      // one thread per (site, channel)
    int block = 256;
    int grid = (total + block - 1) / block;
    hipLaunchKernelGGL(kde_kernel, dim3(grid), dim3(block), 0, stream, x, out, nsites);
}